// Round 1
// baseline (534.427 us; speedup 1.0000x reference)
//
#include <hip/hip_runtime.h>

typedef unsigned short u16;
typedef __attribute__((ext_vector_type(4))) float  f32x4;
typedef __attribute__((ext_vector_type(4))) int    i32x4;
typedef __attribute__((ext_vector_type(4))) unsigned u32x4;
typedef __attribute__((ext_vector_type(8))) short  shortx8;

__device__ __constant__ float NF4C[16] = {
    -1.0f, -0.6962f, -0.5251f, -0.3949f, -0.2844f, -0.1848f, -0.0911f, 0.0f,
     0.0796f, 0.1609f, 0.2461f, 0.3379f, 0.4407f, 0.5626f, 0.723f, 1.0f};

__device__ __forceinline__ unsigned f2bf(float f) {
    unsigned u = __float_as_uint(f);
    return (u + 0x7FFFu + ((u >> 16) & 1u)) >> 16;   // RNE
}

__device__ __forceinline__ void ld_lds16(const u16* g, u16* l) {
    __builtin_amdgcn_global_load_lds(
        (const __attribute__((address_space(1))) void*)g,
        (__attribute__((address_space(3))) void*)l,
        16, 0, 0);
}

// ---------------- preprocessing (unchanged) ----------------

__global__ __launch_bounds__(256) void cvt_x(const float* __restrict__ x,
                                             u16* __restrict__ xb) {
    const size_t i = ((size_t)blockIdx.x * 256 + threadIdx.x) * 8;
    f32x4 f0 = __builtin_nontemporal_load((const f32x4*)(x + i));      // read-once
    f32x4 f1 = __builtin_nontemporal_load((const f32x4*)(x + i + 4));
    u32x4 o;
    o[0] = f2bf(f0[0]) | (f2bf(f0[1]) << 16);
    o[1] = f2bf(f0[2]) | (f2bf(f0[3]) << 16);
    o[2] = f2bf(f1[0]) | (f2bf(f1[1]) << 16);
    o[3] = f2bf(f1[2]) | (f2bf(f1[3]) << 16);
    *(u32x4*)(xb + i) = o;   // cached: GEMM re-reads from L2/L3
}

__global__ __launch_bounds__(256) void deq_w(const int* __restrict__ qi,
                                             const float* __restrict__ sc,
                                             u16* __restrict__ wb) {
    const size_t i = ((size_t)blockIdx.x * 256 + threadIdx.x) * 8;
    const float s = sc[i >> 10];          // 8 consecutive elems share one 1024-block
    i32x4 q0 = __builtin_nontemporal_load((const i32x4*)(qi + i));     // read-once
    i32x4 q1 = __builtin_nontemporal_load((const i32x4*)(qi + i + 4));
    u32x4 o;
    o[0] = f2bf(NF4C[q0[0]] * s) | (f2bf(NF4C[q0[1]] * s) << 16);
    o[1] = f2bf(NF4C[q0[2]] * s) | (f2bf(NF4C[q0[3]] * s) << 16);
    o[2] = f2bf(NF4C[q1[0]] * s) | (f2bf(NF4C[q1[1]] * s) << 16);
    o[3] = f2bf(NF4C[q1[2]] * s) | (f2bf(NF4C[q1[3]] * s) << 16);
    *(u32x4*)(wb + i) = o;
}

// ---------------- main GEMM: 256x256 tile, 8 waves, counted-vmcnt pipeline ----------
// A: [M,K] bf16 row-major (x), B: [N,K] bf16 row-major (W) -> C = A*B^T, fp32 [M,N]
//
// R4: the 2-barrier/__syncthreads structure was pinned at ~904 TF (the m97-class
// ceiling: vmcnt(0)+lgkmcnt(0) drain before every barrier). This version applies
// T3+T4+T5: 4-slot LDS ring (stage tile kt+2 into slot (kt+2)%4 while reading slot
// kt%4 -> staging never touches a slot being read), raw s_barrier only, counted
// s_waitcnt vmcnt(4) once per K-tile (never 0 in the main loop), 2 phases per
// K-tile with ds_read || global_load_lds || MFMA interleave, setprio(1) around
// each 16-MFMA cluster.
//
// vmcnt ledger (4 global_load_lds per K-tile, 2 per phase):
//   prologue: issue tiles 0,1 (8 loads), vmcnt(4) -> tile0 landed, tile1 in flight.
//   group kt: issue tile kt+2 (4 loads); end-of-group vmcnt(4) -> tile kt+1 landed
//   (its 4 loads are the oldest outstanding), tile kt+2's 4 stay in flight.
//   Tail: kt=126 stages nothing, vmcnt(0) lands tile 127; kt=127 no wait.
//
// XOR bank swizzle (verified 0-conflict in R2, unchanged): LDS chunk slot (row,c)
// holds global chunk c ^ ((row>>1)&3); staging lane fetches (t&3)^((t>>3)&3);
// fragment reads use key (quad ^ ((r16>>1)&3)).

#define BM 256
#define BN 256
#define BK 32

template<bool STAGE, int VMC>
__device__ __forceinline__ void ktile(const u16* Ar, const u16* Br,
                                      const u16* gsa, const u16* gsb,
                                      u16* lda, u16* ldb,
                                      int wm128, int wn64, int r16, int xsw,
                                      f32x4 (&acc)[8][4]) {
    constexpr int K = 4096;
    shortx8 af[4], bf[4], ag[4];

    // ---- phase A: C rows [wm128, wm128+64) ----
#pragma unroll
    for (int i = 0; i < 4; i++)
        af[i] = *(const shortx8*)&Ar[(wm128 + i * 16 + r16) * BK + xsw];
#pragma unroll
    for (int j = 0; j < 4; j++)
        bf[j] = *(const shortx8*)&Br[(wn64 + j * 16 + r16) * BK + xsw];
    if constexpr (STAGE) {
        ld_lds16(gsa,           lda);            // A-tile of kt+2, rows 0-127
        ld_lds16(gsa + 128 * K, lda + 4096);     // rows 128-255
    }
    __builtin_amdgcn_s_barrier();
    asm volatile("s_waitcnt lgkmcnt(0)" ::: "memory");
    __builtin_amdgcn_sched_barrier(0);           // rule #18: pin MFMA after the wait
    __builtin_amdgcn_s_setprio(1);
#pragma unroll
    for (int i = 0; i < 4; i++)
#pragma unroll
        for (int j = 0; j < 4; j++)
            acc[i][j] = __builtin_amdgcn_mfma_f32_16x16x32_bf16(
                af[i], bf[j], acc[i][j], 0, 0, 0);
    __builtin_amdgcn_s_setprio(0);
    __builtin_amdgcn_s_barrier();

    // ---- phase B: C rows [wm128+64, wm128+128) ----
#pragma unroll
    for (int i = 0; i < 4; i++)
        ag[i] = *(const shortx8*)&Ar[(wm128 + 64 + i * 16 + r16) * BK + xsw];
    if constexpr (STAGE) {
        ld_lds16(gsb,           ldb);            // B-tile of kt+2
        ld_lds16(gsb + 128 * K, ldb + 4096);
    }
    __builtin_amdgcn_s_barrier();
    asm volatile("s_waitcnt lgkmcnt(0)" ::: "memory");
    __builtin_amdgcn_sched_barrier(0);
    __builtin_amdgcn_s_setprio(1);
#pragma unroll
    for (int i = 0; i < 4; i++)
#pragma unroll
        for (int j = 0; j < 4; j++)
            acc[4 + i][j] = __builtin_amdgcn_mfma_f32_16x16x32_bf16(
                ag[i], bf[j], acc[4 + i][j], 0, 0, 0);
    __builtin_amdgcn_s_setprio(0);
    if constexpr (VMC == 4) {
        asm volatile("s_waitcnt vmcnt(4)" ::: "memory");   // tile kt+1 landed
    } else if constexpr (VMC == 0) {
        asm volatile("s_waitcnt vmcnt(0)" ::: "memory");   // tail: tile 127 landed
    }
    __builtin_amdgcn_s_barrier();
}

__global__ __launch_bounds__(512, 2) void gemm_bt(const u16* __restrict__ A,
                                                  const u16* __restrict__ B,
                                                  float* __restrict__ C) {
    constexpr int K = 4096, N = 4096;
    __shared__ __align__(16) u16 As[4][BM * BK];   // 4 x 16 KiB
    __shared__ __align__(16) u16 Bs[4][BN * BK];   // 4 x 16 KiB  -> 128 KiB total

    const int t    = threadIdx.x;
    const int wave = t >> 6;
    const int lane = t & 63;
    const int quad = lane >> 4;
    const int r16  = lane & 15;

    // XCD swizzle: id%8 = XCD; each XCD covers 4 m-tiles x 16 n-tiles (bijective, 512%8==0)
    const int id  = blockIdx.x;        // 0..511
    const int xcd = id & 7;
    const int loc = id >> 3;           // 0..63
    const int bm  = (xcd * 4 + (loc >> 4)) * BM;   // 0..31 * 256
    const int bn  = (loc & 15) * BN;               // 0..15 * 256

    // staging: thread t covers row t>>2 (0..127), swizzled 16B chunk (t&3)^((t>>3)&3)
    const int srow = t >> 2;
    const int csw  = (((t & 3) ^ ((t >> 3) & 3))) * 8;  // swizzled col (u16 units)
    const u16* gA0 = A + (size_t)(bm + srow) * K + csw;
    const u16* gB0 = B + (size_t)(bn + srow) * K + csw;

    const int wm128 = (wave >> 2) * 128;   // wave tile 128(m) x 64(n), 2x4 waves
    const int wn64  = (wave & 3) * 64;
    const int xsw   = (quad ^ ((r16 >> 1) & 3)) * 8;    // fragment-read swizzle key
    const int lbase = wave * 512;          // wave-uniform LDS stage base (u16 units)

    f32x4 acc[8][4];
#pragma unroll
    for (int i = 0; i < 8; i++)
#pragma unroll
        for (int j = 0; j < 4; j++) acc[i][j] = (f32x4)0.0f;

    // prologue: stage tiles 0 and 1 (order matters for the vmcnt ledger)
    ld_lds16(gA0,                &As[0][lbase]);
    ld_lds16(gA0 + 128 * K,      &As[0][lbase + 4096]);
    ld_lds16(gB0,                &Bs[0][lbase]);
    ld_lds16(gB0 + 128 * K,      &Bs[0][lbase + 4096]);
    ld_lds16(gA0 + BK,           &As[1][lbase]);
    ld_lds16(gA0 + BK + 128 * K, &As[1][lbase + 4096]);
    ld_lds16(gB0 + BK,           &Bs[1][lbase]);
    ld_lds16(gB0 + BK + 128 * K, &Bs[1][lbase + 4096]);
    asm volatile("s_waitcnt vmcnt(4)" ::: "memory");   // tile 0 landed
    __builtin_amdgcn_s_barrier();

    const u16* gsa = gA0 + 2 * BK;   // staging source for tile kt+2
    const u16* gsb = gB0 + 2 * BK;
#pragma unroll 1
    for (int kt = 0; kt < 126; ++kt) {
        const int rd = kt & 3;
        const int st = (kt + 2) & 3;
        ktile<true, 4>(&As[rd][0], &Bs[rd][0], gsa, gsb,
                       &As[st][lbase], &Bs[st][lbase],
                       wm128, wn64, r16, xsw, acc);
        gsa += BK;
        gsb += BK;
    }
    // tail: tiles 126 (drain tile 127's loads) and 127
    ktile<false, 0>(&As[126 & 3][0], &Bs[126 & 3][0], nullptr, nullptr,
                    nullptr, nullptr, wm128, wn64, r16, xsw, acc);
    ktile<false, -1>(&As[127 & 3][0], &Bs[127 & 3][0], nullptr, nullptr,
                     nullptr, nullptr, wm128, wn64, r16, xsw, acc);

    // epilogue: C/D layout col=lane&15, row=quad*4+reg  [verified m89]
#pragma unroll
    for (int i = 0; i < 8; i++) {
        const int row0 = bm + wm128 + i * 16 + quad * 4;
#pragma unroll
        for (int j = 0; j < 4; j++) {
            const int col = bn + wn64 + j * 16 + r16;
            float* cp = &C[(size_t)row0 * N + col];
#pragma unroll
            for (int v = 0; v < 4; ++v)
                cp[(size_t)v * N] = acc[i][j][v];
        }
    }
}

// ---------------- fallback (ws too small): fp32 tiled, dequant on the fly ----------------

__global__ __launch_bounds__(256) void fallback_gemm(const float* __restrict__ x,
                                                     const int* __restrict__ qi,
                                                     const float* __restrict__ sc,
                                                     float* __restrict__ y) {
    __shared__ float xs[16][16];
    __shared__ float wsm[16][17];
    const int tx = threadIdx.x, ty = threadIdx.y;
    const int m = blockIdx.y * 16 + ty;
    const int nrow = blockIdx.x * 16 + ty;   // W row loaded by this thread
    float acc = 0.f;
    for (int k0 = 0; k0 < 4096; k0 += 16) {
        xs[ty][tx] = x[(size_t)m * 4096 + k0 + tx];
        const size_t fi = (size_t)nrow * 4096 + k0 + tx;
        wsm[ty][tx] = NF4C[qi[fi]] * sc[fi >> 10];
        __syncthreads();
#pragma unroll
        for (int kk = 0; kk < 16; kk++) acc += xs[ty][kk] * wsm[tx][kk];
        __syncthreads();
    }
    y[(size_t)m * 4096 + blockIdx.x * 16 + tx] = acc;
}

// ---------------- launch ----------------

extern "C" void kernel_launch(void* const* d_in, const int* in_sizes, int n_in,
                              void* d_out, int out_size, void* d_ws, size_t ws_size,
                              hipStream_t stream) {
    const float* x  = (const float*)d_in[0];
    const int*   qi = (const int*)d_in[1];
    const float* sc = (const float*)d_in[2];
    float* y = (float*)d_out;

    const int M = 8192, N = 4096, K = 4096;
    const size_t xb_bytes = (size_t)M * K * 2;   // 64 MiB
    const size_t wb_bytes = (size_t)N * K * 2;   // 32 MiB

    if (ws_size >= xb_bytes + wb_bytes) {
        u16* xb = (u16*)d_ws;
        u16* wb = (u16*)((char*)d_ws + xb_bytes);
        cvt_x<<<(M * K) / (256 * 8), 256, 0, stream>>>(x, xb);
        deq_w<<<(N * K) / (256 * 8), 256, 0, stream>>>(qi, sc, wb);
        gemm_bt<<<(M / BM) * (N / BN), 512, 0, stream>>>(xb, wb, y);
    } else {
        dim3 block(16, 16);
        dim3 grid(N / 16, M / 16);
        fallback_gemm<<<grid, block, 0, stream>>>(x, qi, sc, y);
    }
}

// Round 2
// 513.621 us; speedup vs baseline: 1.0405x; 1.0405x over previous
//
#include <hip/hip_runtime.h>

typedef unsigned short u16;
typedef __attribute__((ext_vector_type(4))) float  f32x4;
typedef __attribute__((ext_vector_type(4))) int    i32x4;
typedef __attribute__((ext_vector_type(4))) unsigned u32x4;
typedef __attribute__((ext_vector_type(8))) short  shortx8;

__device__ __constant__ float NF4C[16] = {
    -1.0f, -0.6962f, -0.5251f, -0.3949f, -0.2844f, -0.1848f, -0.0911f, 0.0f,
     0.0796f, 0.1609f, 0.2461f, 0.3379f, 0.4407f, 0.5626f, 0.723f, 1.0f};

__device__ __forceinline__ unsigned f2bf(float f) {
    unsigned u = __float_as_uint(f);
    return (u + 0x7FFFu + ((u >> 16) & 1u)) >> 16;   // RNE
}

__device__ __forceinline__ void ld_lds16(const u16* g, u16* l) {
    __builtin_amdgcn_global_load_lds(
        (const __attribute__((address_space(1))) void*)g,
        (__attribute__((address_space(3))) void*)l,
        16, 0, 0);
}

// ---------------- preprocessing (unchanged) ----------------

__global__ __launch_bounds__(256) void cvt_x(const float* __restrict__ x,
                                             u16* __restrict__ xb) {
    const size_t i = ((size_t)blockIdx.x * 256 + threadIdx.x) * 8;
    f32x4 f0 = __builtin_nontemporal_load((const f32x4*)(x + i));      // read-once
    f32x4 f1 = __builtin_nontemporal_load((const f32x4*)(x + i + 4));
    u32x4 o;
    o[0] = f2bf(f0[0]) | (f2bf(f0[1]) << 16);
    o[1] = f2bf(f0[2]) | (f2bf(f0[3]) << 16);
    o[2] = f2bf(f1[0]) | (f2bf(f1[1]) << 16);
    o[3] = f2bf(f1[2]) | (f2bf(f1[3]) << 16);
    *(u32x4*)(xb + i) = o;   // cached: GEMM re-reads from L2/L3
}

__global__ __launch_bounds__(256) void deq_w(const int* __restrict__ qi,
                                             const float* __restrict__ sc,
                                             u16* __restrict__ wb) {
    const size_t i = ((size_t)blockIdx.x * 256 + threadIdx.x) * 8;
    const float s = sc[i >> 10];          // 8 consecutive elems share one 1024-block
    i32x4 q0 = __builtin_nontemporal_load((const i32x4*)(qi + i));     // read-once
    i32x4 q1 = __builtin_nontemporal_load((const i32x4*)(qi + i + 4));
    u32x4 o;
    o[0] = f2bf(NF4C[q0[0]] * s) | (f2bf(NF4C[q0[1]] * s) << 16);
    o[1] = f2bf(NF4C[q0[2]] * s) | (f2bf(NF4C[q0[3]] * s) << 16);
    o[2] = f2bf(NF4C[q1[0]] * s) | (f2bf(NF4C[q1[1]] * s) << 16);
    o[3] = f2bf(NF4C[q1[2]] * s) | (f2bf(NF4C[q1[3]] * s) << 16);
    *(u32x4*)(wb + i) = o;
}

// ---------------- main GEMM: 256x128 tile, 3-slot ring, counted vmcnt, free-run ----
// A: [M,K] bf16 row-major (x), B: [N,K] bf16 row-major (W) -> C = A*B^T, fp32 [M,N]
//
// R5 post-mortem of R4 (843 TF, regression): the 8-phase hybrid added
// sched_barrier(0) (m141 pathology: forced full lgkm drain + scheduling wall
// before every MFMA cluster) and 4 lockstep barriers/K-tile at 1 block/CU
// (serializes LDS and MFMA phases CU-wide; gave away R3's 2-block/CU implicit
// overlap, m114). This version keeps ONLY the mechanistically-sound piece —
// staging never drains (counted vmcnt, never 0 in the main loop) — on top of
// the R3 geometry:
//   * 3-slot LDS ring (72 KiB -> 2 blocks/CU preserved), distance-2 prefetch:
//     iter kt reads slot kt%3, stages tile kt+2 into slot (kt+2)%3.
//   * ONE raw s_barrier (asm, memory clobber) + ONE s_waitcnt vmcnt(6) per
//     K-tile. No __syncthreads, no lgkm asm, no sched_barrier, no phase bars.
//     Compiler keeps its fine-grained lgkmcnt interleave of ds_read vs MFMA.
// vmcnt ledger (6 global_load_lds per wave per K-tile):
//   prologue: stage tiles 0,1 (12 loads), vmcnt(6) -> tile 0 landed; barrier.
//   iter kt: stage tile kt+2 (6 loads); ... ; vmcnt(6) -> drains tile kt+1
//   (oldest 6), tile kt+2 stays in flight; barrier.
//   WAR: slot (kt+2)%3 == slot (kt-1)%3; its readers finished before passing
//   iter kt-1's barrier, which every wave crossed before iter kt issues.
//   Tail: iter 126 drains vmcnt(0) (tile 127 lands); iter 127 computes only.
//
// XOR bank swizzle (verified 0-conflict in R2): LDS chunk slot (row,c) holds
// global chunk c ^ ((row>>1)&3); staging lane fetches (t&3)^((t>>3)&3);
// fragment reads use key (quad ^ ((r16>>1)&3)).

#define BM 256
#define BN 128
#define BK 32
#define SLOT_A (BM * BK)   // 8192 u16 = 16 KiB
#define SLOT_B (BN * BK)   // 4096 u16 =  8 KiB

template<int RD, int ST, int VMC>
__device__ __forceinline__ void ktile(const u16* gsa, const u16* gsb,
                                      u16* Asb, u16* Bsb, int lao,
                                      int wm, int wn, int r16, int xsw,
                                      f32x4 (&acc)[8][4]) {
    constexpr int K = 4096;
    if constexpr (ST >= 0) {          // stage tile kt+2 into ring slot ST
        u16* la = Asb + ST * SLOT_A + lao;
        u16* lb = Bsb + ST * SLOT_B + lao;
        ld_lds16(gsa,           la);
        ld_lds16(gsa +  64 * K, la + 2048);
        ld_lds16(gsa + 128 * K, la + 4096);
        ld_lds16(gsa + 192 * K, la + 6144);
        ld_lds16(gsb,           lb);
        ld_lds16(gsb +  64 * K, lb + 2048);
    }
    const u16* Ar = Asb + RD * SLOT_A;
    const u16* Br = Bsb + RD * SLOT_B;
    shortx8 af[8], bf[4];
#pragma unroll
    for (int i = 0; i < 8; i++)
        af[i] = *(const shortx8*)&Ar[(wm + i * 16 + r16) * BK + xsw];
#pragma unroll
    for (int j = 0; j < 4; j++)
        bf[j] = *(const shortx8*)&Br[(wn + j * 16 + r16) * BK + xsw];
#pragma unroll
    for (int i = 0; i < 8; i++)
#pragma unroll
        for (int j = 0; j < 4; j++)
            acc[i][j] = __builtin_amdgcn_mfma_f32_16x16x32_bf16(
                af[i], bf[j], acc[i][j], 0, 0, 0);
    if constexpr (VMC == 6) {
        asm volatile("s_waitcnt vmcnt(6)" ::: "memory");   // tile kt+1 landed
        asm volatile("s_barrier" ::: "memory");
    } else if constexpr (VMC == 0) {
        asm volatile("s_waitcnt vmcnt(0)" ::: "memory");   // tail: tile 127 landed
        asm volatile("s_barrier" ::: "memory");
    }                                                      // VMC<0: last tile, no sync
}

__global__ __launch_bounds__(256, 2) void gemm_bt(const u16* __restrict__ A,
                                                  const u16* __restrict__ B,
                                                  float* __restrict__ C) {
    constexpr int K = 4096, N = 4096;
    __shared__ __align__(16) u16 As[3 * SLOT_A];   // 48 KiB
    __shared__ __align__(16) u16 Bs[3 * SLOT_B];   // 24 KiB -> 72 KiB total

    const int t    = threadIdx.x;
    const int wave = t >> 6;
    const int lane = t & 63;
    const int quad = lane >> 4;
    const int r16  = lane & 15;

    // XCD swizzle: id%8 = XCD; each XCD covers 4 bm-rows x 32 bn-cols, bn-fast.
    const int id  = blockIdx.x;        // 0..1023
    const int xcd = id & 7;
    const int loc = id >> 3;           // 0..127
    const int bm  = (xcd * 4 + (loc >> 5)) * BM;   // 0..31 * 256
    const int bn  = (loc & 31) * BN;               // 0..31 * 128

    // staging: thread t covers row (g*64 + t>>2), swizzled 16B chunk (t&3)^((t>>3)&3)
    const int srow = t >> 2;                            // 0..63
    const int csw  = (((t & 3) ^ ((t >> 3) & 3))) * 8;  // swizzled col (u16 units)
    const u16* gA0 = A + (size_t)(bm + srow) * K + csw;
    const u16* gB0 = B + (size_t)(bn + srow) * K + csw;
    const int lao  = wave * 512;   // wave-uniform LDS stage base (u16 units)

    const int wm = (wave >> 1) * 128;   // wave tile 128(m) x 64(n)
    const int wn = (wave & 1) * 64;
    const int xsw = (quad ^ ((r16 >> 1) & 3)) * 8;   // fragment-read swizzle key

    f32x4 acc[8][4];
#pragma unroll
    for (int i = 0; i < 8; i++)
#pragma unroll
        for (int j = 0; j < 4; j++) acc[i][j] = (f32x4)0.0f;

    // prologue: stage tile 0 -> slot 0, tile 1 -> slot 1
    {
        u16* la = &As[lao];
        u16* lb = &Bs[lao];
        ld_lds16(gA0,           la);
        ld_lds16(gA0 +  64 * K, la + 2048);
        ld_lds16(gA0 + 128 * K, la + 4096);
        ld_lds16(gA0 + 192 * K, la + 6144);
        ld_lds16(gB0,           lb);
        ld_lds16(gB0 +  64 * K, lb + 2048);
        la = &As[SLOT_A + lao];
        lb = &Bs[SLOT_B + lao];
        ld_lds16(gA0 + BK,           la);
        ld_lds16(gA0 + BK +  64 * K, la + 2048);
        ld_lds16(gA0 + BK + 128 * K, la + 4096);
        ld_lds16(gA0 + BK + 192 * K, la + 6144);
        ld_lds16(gB0 + BK,           lb);
        ld_lds16(gB0 + BK +  64 * K, lb + 2048);
    }
    asm volatile("s_waitcnt vmcnt(6)" ::: "memory");   // tile 0 landed
    asm volatile("s_barrier" ::: "memory");

    const u16* gsa = gA0 + 2 * BK;   // staging source for tile kt+2
    const u16* gsb = gB0 + 2 * BK;
#pragma unroll 1
    for (int kt = 0; kt < 126; kt += 3) {   // tile t lives in slot t%3
        ktile<0, 2, 6>(gsa, gsb, As, Bs, lao, wm, wn, r16, xsw, acc);
        gsa += BK; gsb += BK;
        ktile<1, 0, 6>(gsa, gsb, As, Bs, lao, wm, wn, r16, xsw, acc);
        gsa += BK; gsb += BK;
        ktile<2, 1, 6>(gsa, gsb, As, Bs, lao, wm, wn, r16, xsw, acc);
        gsa += BK; gsb += BK;
    }
    // tails: kt=126 (slot 0, drain tile 127), kt=127 (slot 1, no sync after)
    ktile<0, -1, 0>(nullptr, nullptr, As, Bs, lao, wm, wn, r16, xsw, acc);
    ktile<1, -1, -1>(nullptr, nullptr, As, Bs, lao, wm, wn, r16, xsw, acc);

    // epilogue: C/D layout col=lane&15, row=quad*4+reg  [verified m89]
#pragma unroll
    for (int i = 0; i < 8; i++) {
        const int row0 = bm + wm + i * 16 + quad * 4;
#pragma unroll
        for (int j = 0; j < 4; j++) {
            const int col = bn + wn + j * 16 + r16;
            float* cp = &C[(size_t)row0 * N + col];
#pragma unroll
            for (int v = 0; v < 4; ++v)
                cp[(size_t)v * N] = acc[i][j][v];
        }
    }
}

// ---------------- fallback (ws too small): fp32 tiled, dequant on the fly ----------------

__global__ __launch_bounds__(256) void fallback_gemm(const float* __restrict__ x,
                                                     const int* __restrict__ qi,
                                                     const float* __restrict__ sc,
                                                     float* __restrict__ y) {
    __shared__ float xs[16][16];
    __shared__ float wsm[16][17];
    const int tx = threadIdx.x, ty = threadIdx.y;
    const int m = blockIdx.y * 16 + ty;
    const int nrow = blockIdx.x * 16 + ty;   // W row loaded by this thread
    float acc = 0.f;
    for (int k0 = 0; k0 < 4096; k0 += 16) {
        xs[ty][tx] = x[(size_t)m * 4096 + k0 + tx];
        const size_t fi = (size_t)nrow * 4096 + k0 + tx;
        wsm[ty][tx] = NF4C[qi[fi]] * sc[fi >> 10];
        __syncthreads();
#pragma unroll
        for (int kk = 0; kk < 16; kk++) acc += xs[ty][kk] * wsm[tx][kk];
        __syncthreads();
    }
    y[(size_t)m * 4096 + blockIdx.x * 16 + tx] = acc;
}

// ---------------- launch ----------------

extern "C" void kernel_launch(void* const* d_in, const int* in_sizes, int n_in,
                              void* d_out, int out_size, void* d_ws, size_t ws_size,
                              hipStream_t stream) {
    const float* x  = (const float*)d_in[0];
    const int*   qi = (const int*)d_in[1];
    const float* sc = (const float*)d_in[2];
    float* y = (float*)d_out;

    const int M = 8192, N = 4096, K = 4096;
    const size_t xb_bytes = (size_t)M * K * 2;   // 64 MiB
    const size_t wb_bytes = (size_t)N * K * 2;   // 32 MiB

    if (ws_size >= xb_bytes + wb_bytes) {
        u16* xb = (u16*)d_ws;
        u16* wb = (u16*)((char*)d_ws + xb_bytes);
        cvt_x<<<(M * K) / (256 * 8), 256, 0, stream>>>(x, xb);
        deq_w<<<(N * K) / (256 * 8), 256, 0, stream>>>(qi, sc, wb);
        gemm_bt<<<(M / BM) * (N / BN), 256, 0, stream>>>(xb, wb, y);
    } else {
        dim3 block(16, 16);
        dim3 grid(N / 16, M / 16);
        fallback_gemm<<<grid, block, 0, stream>>>(x, qi, sc, y);
    }
}

// Round 3
// 491.770 us; speedup vs baseline: 1.0867x; 1.0444x over previous
//
#include <hip/hip_runtime.h>

typedef unsigned short u16;
typedef __attribute__((ext_vector_type(4))) float  f32x4;
typedef __attribute__((ext_vector_type(4))) int    i32x4;
typedef __attribute__((ext_vector_type(4))) unsigned u32x4;
typedef __attribute__((ext_vector_type(8))) short  shortx8;

__device__ __constant__ float NF4C[16] = {
    -1.0f, -0.6962f, -0.5251f, -0.3949f, -0.2844f, -0.1848f, -0.0911f, 0.0f,
     0.0796f, 0.1609f, 0.2461f, 0.3379f, 0.4407f, 0.5626f, 0.723f, 1.0f};

__device__ __forceinline__ unsigned f2bf(float f) {
    unsigned u = __float_as_uint(f);
    return (u + 0x7FFFu + ((u >> 16) & 1u)) >> 16;   // RNE
}

__device__ __forceinline__ void ld_lds16(const u16* g, u16* l) {
    __builtin_amdgcn_global_load_lds(
        (const __attribute__((address_space(1))) void*)g,
        (__attribute__((address_space(3))) void*)l,
        16, 0, 0);
}

// ---------------- preprocessing (unchanged) ----------------

__global__ __launch_bounds__(256) void cvt_x(const float* __restrict__ x,
                                             u16* __restrict__ xb) {
    const size_t i = ((size_t)blockIdx.x * 256 + threadIdx.x) * 8;
    f32x4 f0 = __builtin_nontemporal_load((const f32x4*)(x + i));      // read-once
    f32x4 f1 = __builtin_nontemporal_load((const f32x4*)(x + i + 4));
    u32x4 o;
    o[0] = f2bf(f0[0]) | (f2bf(f0[1]) << 16);
    o[1] = f2bf(f0[2]) | (f2bf(f0[3]) << 16);
    o[2] = f2bf(f1[0]) | (f2bf(f1[1]) << 16);
    o[3] = f2bf(f1[2]) | (f2bf(f1[3]) << 16);
    *(u32x4*)(xb + i) = o;   // cached: GEMM re-reads from L2/L3
}

__global__ __launch_bounds__(256) void deq_w(const int* __restrict__ qi,
                                             const float* __restrict__ sc,
                                             u16* __restrict__ wb) {
    const size_t i = ((size_t)blockIdx.x * 256 + threadIdx.x) * 8;
    const float s = sc[i >> 10];          // 8 consecutive elems share one 1024-block
    i32x4 q0 = __builtin_nontemporal_load((const i32x4*)(qi + i));     // read-once
    i32x4 q1 = __builtin_nontemporal_load((const i32x4*)(qi + i + 4));
    u32x4 o;
    o[0] = f2bf(NF4C[q0[0]] * s) | (f2bf(NF4C[q0[1]] * s) << 16);
    o[1] = f2bf(NF4C[q0[2]] * s) | (f2bf(NF4C[q0[3]] * s) << 16);
    o[2] = f2bf(NF4C[q1[0]] * s) | (f2bf(NF4C[q1[1]] * s) << 16);
    o[3] = f2bf(NF4C[q1[2]] * s) | (f2bf(NF4C[q1[3]] * s) << 16);
    *(u32x4*)(wb + i) = o;
}

// ---------------- main GEMM: faithful 8-phase (m201-class) port -------------------
// A: [M,K] bf16 row-major (x), B: [N,K] bf16 row-major (W) -> C = A*B^T, fp32 [M,N]
//
// 256x256 tile, BK=64, 8 waves (512 thr), wave tile 128x64 (2Mx4N). LDS: 2 buffers
// x (A 32KiB + B 32KiB) = 128 KiB. 4 phases per K-tile; per phase: {4-or-8
// ds_read_b128, 2 global_load_lds (one quarter = 8KiB), BAR, lgkmcnt(0), setprio(1),
// 16 MFMA, setprio(0), [vmcnt(4) at P1/P4], BAR}. No sched_barrier (m141), no
// __syncthreads, vmcnt never 0 in steady state (T3+T4), setprio (T5).
//
// Swizzle (BK=64, both-sides per rule #21): LDS slot (row, c) holds global 16B
// chunk c ^ (row&7). Stage: lane L sources chunk (L&7)^(L>>3) of row w*8+(L>>3);
// linear LDS dest. Read: frag (row, kstep k, quad q) reads slot (k*4+q)^(row&7).
// Conflict check: 64 lanes -> 2 lanes/bank = free (m136).
//
// Staging ledger (quarters: Aq0..3 = rows 0-63/64-127/128-191/192-255, Bq0..3 same;
// tile t lives in buf t&1; group u = 4 phases computing tile u):
//   stage slots:  u.P1: Bq2,Bq3(t=u+1)  u.P2: Aq0,Aq2(u+1)  u.P3: Aq1,Aq3(u+1)
//                 u.P4: Bq0,Bq1(t=u+2, into CURRENT buf)
//   WAR: dual barriers make "stage at phase p, region last-read at phase p-1" safe
//        (readers pass lgkmcnt(0) before BAR2(p-1); stager issues after BAR2(p-1)).
//        Aq1/Aq3 of tile u last read u.P4 -> staged u+1.P3 OK; B last read u.P3 ->
//        Bq01(u+2) staged u.P4 OK.
//   Visibility: vmcnt(4)+BAR at each P1-end and P4-end.
//        u.P4-end outstanding (old->new): [P1 Bq23][P2 Aq02][P3 Aq13][P4 Bq01'] = 8
//        -> vmcnt(4) drains Bq23,Aq02 (+ older Bq01 from u-1.P4): everything
//        consumed at u+1.P1. u+1.P1-end: [Aq13][Bq01'][P1 Bq23'] = 6 -> vmcnt(4)
//        drains Aq13, consumed u+1.P2. Steady in-flight 4..10 loads/wave.
//   Tail: group 62 stages tile 63 at P1-P3, vmcnt(0) at P4; group 63 computes only.

#define BM 256
#define BN 256
#define BK 64

template<int MODE>   // 0 = steady, 1 = penultimate (no P4 stage, vmcnt0), 2 = last
__device__ __forceinline__ void kgroup(
    const u16* __restrict__ Ar, const u16* __restrict__ Br,   // read bufs
    u16* dA1, u16* dB1,          // stage dest wave-bases, buf^1 (tile u+1)
    u16* dBc,                    // stage dest wave-base, current buf (tile u+2 B)
    const u16* gA1, const u16* gB1,   // per-lane staging src, tile u+1
    int wm, int wn, int r16, int c0, int c1,
    f32x4 (&acc)[8][4])
{
    constexpr size_t K = 4096;
    shortx8 a[4], b[4];

    // ---- P1: acc[0..3][*], kstep0 (8 ds_read) ----
#pragma unroll
    for (int j = 0; j < 4; j++)
        b[j] = *(const shortx8*)&Br[(wn + j * 16 + r16) * 64 + c0 * 8];
#pragma unroll
    for (int i = 0; i < 4; i++)
        a[i] = *(const shortx8*)&Ar[(wm + i * 16 + r16) * 64 + c0 * 8];
    if constexpr (MODE <= 1) {
        ld_lds16(gB1 + 128 * K, dB1 + 128 * 64);   // Bq2 of u+1
        ld_lds16(gB1 + 192 * K, dB1 + 192 * 64);   // Bq3
    }
    asm volatile("s_barrier" ::: "memory");
    asm volatile("s_waitcnt lgkmcnt(0)" ::: "memory");
    __builtin_amdgcn_s_setprio(1);
#pragma unroll
    for (int i = 0; i < 4; i++)
#pragma unroll
        for (int j = 0; j < 4; j++)
            acc[i][j] = __builtin_amdgcn_mfma_f32_16x16x32_bf16(a[i], b[j], acc[i][j], 0, 0, 0);
    __builtin_amdgcn_s_setprio(0);
    if constexpr (MODE <= 1) asm volatile("s_waitcnt vmcnt(4)" ::: "memory");
    asm volatile("s_barrier" ::: "memory");

    // ---- P2: acc[4..7][*], kstep0 (4 ds_read; b[] reused) ----
#pragma unroll
    for (int i = 0; i < 4; i++)
        a[i] = *(const shortx8*)&Ar[(wm + 64 + i * 16 + r16) * 64 + c0 * 8];
    if constexpr (MODE <= 1) {
        ld_lds16(gA1,           dA1);              // Aq0 of u+1
        ld_lds16(gA1 + 128 * K, dA1 + 128 * 64);   // Aq2
    }
    asm volatile("s_barrier" ::: "memory");
    asm volatile("s_waitcnt lgkmcnt(0)" ::: "memory");
    __builtin_amdgcn_s_setprio(1);
#pragma unroll
    for (int i = 0; i < 4; i++)
#pragma unroll
        for (int j = 0; j < 4; j++)
            acc[4 + i][j] = __builtin_amdgcn_mfma_f32_16x16x32_bf16(a[i], b[j], acc[4 + i][j], 0, 0, 0);
    __builtin_amdgcn_s_setprio(0);
    asm volatile("s_barrier" ::: "memory");

    // ---- P3: acc[0..3][*], kstep1 (8 ds_read) ----
#pragma unroll
    for (int j = 0; j < 4; j++)
        b[j] = *(const shortx8*)&Br[(wn + j * 16 + r16) * 64 + c1 * 8];
#pragma unroll
    for (int i = 0; i < 4; i++)
        a[i] = *(const shortx8*)&Ar[(wm + i * 16 + r16) * 64 + c1 * 8];
    if constexpr (MODE <= 1) {
        ld_lds16(gA1 +  64 * K, dA1 +  64 * 64);   // Aq1 of u+1
        ld_lds16(gA1 + 192 * K, dA1 + 192 * 64);   // Aq3
    }
    asm volatile("s_barrier" ::: "memory");
    asm volatile("s_waitcnt lgkmcnt(0)" ::: "memory");
    __builtin_amdgcn_s_setprio(1);
#pragma unroll
    for (int i = 0; i < 4; i++)
#pragma unroll
        for (int j = 0; j < 4; j++)
            acc[i][j] = __builtin_amdgcn_mfma_f32_16x16x32_bf16(a[i], b[j], acc[i][j], 0, 0, 0);
    __builtin_amdgcn_s_setprio(0);
    asm volatile("s_barrier" ::: "memory");

    // ---- P4: acc[4..7][*], kstep1 (4 ds_read) ----
#pragma unroll
    for (int i = 0; i < 4; i++)
        a[i] = *(const shortx8*)&Ar[(wm + 64 + i * 16 + r16) * 64 + c1 * 8];
    if constexpr (MODE == 0) {
        ld_lds16(gB1 + 64,           dBc);             // Bq0 of u+2 -> current buf
        ld_lds16(gB1 + 64 + 64 * K,  dBc + 64 * 64);   // Bq1
    }
    asm volatile("s_barrier" ::: "memory");
    asm volatile("s_waitcnt lgkmcnt(0)" ::: "memory");
    __builtin_amdgcn_s_setprio(1);
#pragma unroll
    for (int i = 0; i < 4; i++)
#pragma unroll
        for (int j = 0; j < 4; j++)
            acc[4 + i][j] = __builtin_amdgcn_mfma_f32_16x16x32_bf16(a[i], b[j], acc[4 + i][j], 0, 0, 0);
    __builtin_amdgcn_s_setprio(0);
    if constexpr (MODE == 0)      asm volatile("s_waitcnt vmcnt(4)" ::: "memory");
    else if constexpr (MODE == 1) asm volatile("s_waitcnt vmcnt(0)" ::: "memory");
    asm volatile("s_barrier" ::: "memory");
}

__global__ __launch_bounds__(512, 2) void gemm_bt(const u16* __restrict__ A,
                                                  const u16* __restrict__ B,
                                                  float* __restrict__ C) {
    constexpr size_t K = 4096;
    constexpr int N = 4096;
    __shared__ __align__(16) u16 As[2][BM * BK];   // 2 x 32 KiB
    __shared__ __align__(16) u16 Bs[2][BN * BK];   // 2 x 32 KiB -> 128 KiB

    const int t    = threadIdx.x;
    const int wave = t >> 6;
    const int lane = t & 63;
    const int quad = lane >> 4;
    const int r16  = lane & 15;

    // XCD swizzle (512 blocks, 512%8==0 bijective): 4 m-tiles x 16 n-tiles per XCD
    const int id  = blockIdx.x;
    const int xcd = id & 7;
    const int loc = id >> 3;                       // 0..63
    const int bm  = (xcd * 4 + (loc >> 4)) * BM;   // 0..31 * 256
    const int bn  = (loc & 15) * BN;               // 0..15 * 256

    // per-lane staging source (pre-swizzled chunk): row w*8+(lane>>3), chunk (lane&7)^(lane>>3)
    const int lrow = (wave << 3) + (lane >> 3);
    const int lch  = (lane & 7) ^ (lane >> 3);
    const u16* sA = A + (size_t)(bm + lrow) * K + lch * 8;
    const u16* sB = B + (size_t)(bn + lrow) * K + lch * 8;

    const int w512 = wave * 512;                   // wave slab offset within a quarter
    u16* dA0 = &As[0][w512];  u16* dA1 = &As[1][w512];
    u16* dB0 = &Bs[0][w512];  u16* dB1 = &Bs[1][w512];

    const int wm = (wave >> 2) * 128;              // wave tile 128(m) x 64(n)
    const int wn = (wave & 3) * 64;
    const int c0 = quad ^ (r16 & 7);               // kstep0 chunk key
    const int c1 = c0 ^ 4;                         // kstep1

    f32x4 acc[8][4];
#pragma unroll
    for (int i = 0; i < 8; i++)
#pragma unroll
        for (int j = 0; j < 4; j++) acc[i][j] = (f32x4)0.0f;

    // prologue: tile 0 (8 quarters) -> buf0; tile 1 Bq0,Bq1 -> buf1; order matters.
#pragma unroll
    for (int r0 = 0; r0 < 256; r0 += 64) {
        ld_lds16(sA + (size_t)r0 * K, dA0 + r0 * 64);
        ld_lds16(sB + (size_t)r0 * K, dB0 + r0 * 64);
    }
    ld_lds16(sB + 64,                 dB1);
    ld_lds16(sB + 64 + (size_t)64 * K, dB1 + 64 * 64);
    asm volatile("s_waitcnt vmcnt(2)" ::: "memory");   // tile 0 landed
    asm volatile("s_barrier" ::: "memory");

    const u16* gA1 = sA + 64;   // staging src base, tile u+1
    const u16* gB1 = sB + 64;
#pragma unroll 1
    for (int u = 0; u < 62; u += 2) {
        kgroup<0>(As[0], Bs[0], dA1, dB1, dB0, gA1, gB1, wm, wn, r16, c0, c1, acc);
        gA1 += 64; gB1 += 64;
        kgroup<0>(As[1], Bs[1], dA0, dB0, dB1, gA1, gB1, wm, wn, r16, c0, c1, acc);
        gA1 += 64; gB1 += 64;
    }
    // group 62 (buf0; stages tile 63 into buf1; vmcnt(0) at P4), group 63 (buf1)
    kgroup<1>(As[0], Bs[0], dA1, dB1, dB0, gA1, gB1, wm, wn, r16, c0, c1, acc);
    kgroup<2>(As[1], Bs[1], dA0, dB0, dB1, gA1, gB1, wm, wn, r16, c0, c1, acc);

    // epilogue: C/D layout col=lane&15, row=quad*4+reg  [verified m89; R1 refcheck'd]
#pragma unroll
    for (int i = 0; i < 8; i++) {
        const int row0 = bm + wm + i * 16 + quad * 4;
#pragma unroll
        for (int j = 0; j < 4; j++) {
            const int col = bn + wn + j * 16 + r16;
            float* cp = &C[(size_t)row0 * N + col];
#pragma unroll
            for (int v = 0; v < 4; ++v)
                cp[(size_t)v * N] = acc[i][j][v];
        }
    }
}

// ---------------- fallback (ws too small): fp32 tiled, dequant on the fly ----------------

__global__ __launch_bounds__(256) void fallback_gemm(const float* __restrict__ x,
                                                     const int* __restrict__ qi,
                                                     const float* __restrict__ sc,
                                                     float* __restrict__ y) {
    __shared__ float xs[16][16];
    __shared__ float wsm[16][17];
    const int tx = threadIdx.x, ty = threadIdx.y;
    const int m = blockIdx.y * 16 + ty;
    const int nrow = blockIdx.x * 16 + ty;   // W row loaded by this thread
    float acc = 0.f;
    for (int k0 = 0; k0 < 4096; k0 += 16) {
        xs[ty][tx] = x[(size_t)m * 4096 + k0 + tx];
        const size_t fi = (size_t)nrow * 4096 + k0 + tx;
        wsm[ty][tx] = NF4C[qi[fi]] * sc[fi >> 10];
        __syncthreads();
#pragma unroll
        for (int kk = 0; kk < 16; kk++) acc += xs[ty][kk] * wsm[tx][kk];
        __syncthreads();
    }
    y[(size_t)m * 4096 + blockIdx.x * 16 + tx] = acc;
}

// ---------------- launch ----------------

extern "C" void kernel_launch(void* const* d_in, const int* in_sizes, int n_in,
                              void* d_out, int out_size, void* d_ws, size_t ws_size,
                              hipStream_t stream) {
    const float* x  = (const float*)d_in[0];
    const int*   qi = (const int*)d_in[1];
    const float* sc = (const float*)d_in[2];
    float* y = (float*)d_out;

    const int M = 8192, N = 4096, K = 4096;
    const size_t xb_bytes = (size_t)M * K * 2;   // 64 MiB
    const size_t wb_bytes = (size_t)N * K * 2;   // 32 MiB

    if (ws_size >= xb_bytes + wb_bytes) {
        u16* xb = (u16*)d_ws;
        u16* wb = (u16*)((char*)d_ws + xb_bytes);
        cvt_x<<<(M * K) / (256 * 8), 256, 0, stream>>>(x, xb);
        deq_w<<<(N * K) / (256 * 8), 256, 0, stream>>>(qi, sc, wb);
        gemm_bt<<<(M / BM) * (N / BN), 512, 0, stream>>>(xb, wb, y);
    } else {
        dim3 block(16, 16);
        dim3 grid(N / 16, M / 16);
        fallback_gemm<<<grid, block, 0, stream>>>(x, qi, sc, y);
    }
}

// Round 4
// 478.282 us; speedup vs baseline: 1.1174x; 1.0282x over previous
//
#include <hip/hip_runtime.h>

typedef unsigned short u16;
typedef __attribute__((ext_vector_type(4))) float  f32x4;
typedef __attribute__((ext_vector_type(4))) int    i32x4;
typedef __attribute__((ext_vector_type(4))) unsigned u32x4;
typedef __attribute__((ext_vector_type(8))) short  shortx8;

__device__ __constant__ float NF4C[16] = {
    -1.0f, -0.6962f, -0.5251f, -0.3949f, -0.2844f, -0.1848f, -0.0911f, 0.0f,
     0.0796f, 0.1609f, 0.2461f, 0.3379f, 0.4407f, 0.5626f, 0.723f, 1.0f};

__device__ __forceinline__ unsigned f2bf(float f) {
    unsigned u = __float_as_uint(f);
    return (u + 0x7FFFu + ((u >> 16) & 1u)) >> 16;   // RNE
}

__device__ __forceinline__ void ld_lds16(const u16* g, u16* l) {
    __builtin_amdgcn_global_load_lds(
        (const __attribute__((address_space(1))) void*)g,
        (__attribute__((address_space(3))) void*)l,
        16, 0, 0);
}

// ---------------- fused preprocessing: one launch, grid-stride ----------------
// x: 8192x4096 f32 -> bf16 (33.55M elems, 8/thread/iter, 8 iters at 2048 blocks)
// W: 4096x4096 NF4 dequant -> bf16 (16.78M elems, 4 iters). Work divides exactly.

__global__ __launch_bounds__(256) void prep(const float* __restrict__ x,
                                            const int* __restrict__ qi,
                                            const float* __restrict__ sc,
                                            u16* __restrict__ xb,
                                            u16* __restrict__ wb) {
    const size_t nthr = (size_t)gridDim.x * 256;
    const size_t tid  = (size_t)blockIdx.x * 256 + threadIdx.x;

    for (size_t c = tid; c < (33554432u / 8); c += nthr) {
        const size_t i = c * 8;
        f32x4 f0 = __builtin_nontemporal_load((const f32x4*)(x + i));   // read-once
        f32x4 f1 = __builtin_nontemporal_load((const f32x4*)(x + i + 4));
        u32x4 o;
        o[0] = f2bf(f0[0]) | (f2bf(f0[1]) << 16);
        o[1] = f2bf(f0[2]) | (f2bf(f0[3]) << 16);
        o[2] = f2bf(f1[0]) | (f2bf(f1[1]) << 16);
        o[3] = f2bf(f1[2]) | (f2bf(f1[3]) << 16);
        *(u32x4*)(xb + i) = o;   // cached: GEMM re-reads from L2/L3
    }
    for (size_t c = tid; c < (16777216u / 8); c += nthr) {
        const size_t i = c * 8;
        const float s = sc[i >> 10];          // 8 consecutive elems share one block
        i32x4 q0 = __builtin_nontemporal_load((const i32x4*)(qi + i));  // read-once
        i32x4 q1 = __builtin_nontemporal_load((const i32x4*)(qi + i + 4));
        u32x4 o;
        o[0] = f2bf(NF4C[q0[0]] * s) | (f2bf(NF4C[q0[1]] * s) << 16);
        o[1] = f2bf(NF4C[q0[2]] * s) | (f2bf(NF4C[q0[3]] * s) << 16);
        o[2] = f2bf(NF4C[q1[0]] * s) | (f2bf(NF4C[q1[1]] * s) << 16);
        o[3] = f2bf(NF4C[q1[2]] * s) | (f2bf(NF4C[q1[3]] * s) << 16);
        *(u32x4*)(wb + i) = o;
    }
}

// ---------------- main GEMM: 256x256, BK=64, minimum-sync ledger -------------------
// A: [M,K] bf16 row-major (x), B: [N,K] bf16 row-major (W) -> C = A*B^T, fp32 [M,N]
//
// R4 post-mortem (R0 40% / R2 41% / R3 43% MfmaUtil): dual-barrier lockstep
// serializes LDS service (~1000 cyc/K-tile/CU) against MFMA (~620 cyc/SIMD) ->
// structural ~43% ceiling. Fix: shrink sync to the provable minimum so waves slip
// and LDS || MFMA overlap across waves.
//
// Per K-tile group u (read buf r=u&1, stage tile u+1 into s=r^1, tile u+2 B-half
// into r): 4 phases P1..P4, each {ds_reads, stage pair, setprio(1) 16 MFMA
// setprio(0)}; sync ONLY:
//   P4pre  BAR          — WAR: Bq01(u+2) is staged into the CURRENT buf's B rows
//                         0..127, which waves with wn in {0,64} read at P1(k0) and
//                         P3(k1). Arrival at P4pre implies every wave consumed its
//                         P3 reads (compiler waits precede its P3 MFMA). A-reads in
//                         P4 touch the A array only — no conflict with the B stage.
//   vmcnt(2) + P4post BAR — drain + publish. Per-wave VMEM windows (bounded by the
//                         asm memory fences): W[u] = {Bq23,Aq02,Aq13}(u+1) 6 loads
//                         issued P1-P3 (internal order irrelevant: drained as one
//                         unit), C[u] = Bq01(u+2) 2 loads issued P4. At u.P4end
//                         outstanding = W[u](6)+C[u](2); vmcnt(2) leaves only C[u].
//                         Hence at u.P4post ALL of tile u+1 ({Bq01 in C[u-1],
//                         drained u.P4end; Bq23/Aq02/Aq13 in W[u]}) is complete and
//                         published. No other barrier or lgkm asm is needed:
//                         buf^1 staging during P1-P3 cannot collide with reads
//                         (tile u-1's last buf^1 reads all precede u-1.P4post).
// Region/reader map used above: wave reads A rows [wm,wm+64) at P1/P3 (k0/k1) and
// [wm+64,wm+128) at P2/P4; B rows [wn,wn+64) every phase. Quarters: Aq02 read at
// P1/P3, Aq13 at P2/P4 (wm in {0,128}); Bq01 by wn in {0,64}, Bq23 by wn in
// {128,192}. Prologue: tile0 (8 loads) + Bq01(1) (2 loads), vmcnt(2) = steady
// entry state. Tail: group 62 stages tile 63 at P1-P3, vmcnt(0); group 63 bare.
//
// XOR bank swizzle (0-conflict, R0/R2/R3-verified): LDS slot (row,c) holds global
// 16B chunk c^(row&7); stage lane L sources chunk (L&7)^(L>>3) of row w*8+(L>>3);
// read key c0 = quad^(r16&7) (kstep0), c1 = c0^4 (kstep1).

#define BM 256
#define BN 256
#define BK 64

template<int MODE>   // 0 = steady, 1 = penultimate (no P4 stage, vmcnt0), 2 = last
__device__ __forceinline__ void kgroup(
    const u16* __restrict__ Ar, const u16* __restrict__ Br,   // read bufs
    u16* dA1, u16* dB1,          // stage dest wave-bases, buf^1 (tile u+1)
    u16* dBc,                    // stage dest wave-base, current buf (tile u+2 B)
    const u16* gA1, const u16* gB1,   // per-lane staging src, tile u+1
    int wm, int wn, int r16, int c0, int c1,
    f32x4 (&acc)[8][4])
{
    constexpr size_t K = 4096;
    shortx8 a[4], a2[4], b[4];

    // ---- P1: acc[0..3], kstep0 ----
#pragma unroll
    for (int j = 0; j < 4; j++)
        b[j] = *(const shortx8*)&Br[(wn + j * 16 + r16) * 64 + c0 * 8];
#pragma unroll
    for (int i = 0; i < 4; i++)
        a[i] = *(const shortx8*)&Ar[(wm + i * 16 + r16) * 64 + c0 * 8];
    if constexpr (MODE <= 1) {
        ld_lds16(gB1 + 128 * K, dB1 + 128 * 64);   // Bq2 of u+1
        ld_lds16(gB1 + 192 * K, dB1 + 192 * 64);   // Bq3
    }
    __builtin_amdgcn_s_setprio(1);
#pragma unroll
    for (int i = 0; i < 4; i++)
#pragma unroll
        for (int j = 0; j < 4; j++)
            acc[i][j] = __builtin_amdgcn_mfma_f32_16x16x32_bf16(a[i], b[j], acc[i][j], 0, 0, 0);
    __builtin_amdgcn_s_setprio(0);

    // ---- P2: acc[4..7], kstep0 (b reused) ----
#pragma unroll
    for (int i = 0; i < 4; i++)
        a2[i] = *(const shortx8*)&Ar[(wm + 64 + i * 16 + r16) * 64 + c0 * 8];
    if constexpr (MODE <= 1) {
        ld_lds16(gA1,           dA1);              // Aq0 of u+1
        ld_lds16(gA1 + 128 * K, dA1 + 128 * 64);   // Aq2
    }
    __builtin_amdgcn_s_setprio(1);
#pragma unroll
    for (int i = 0; i < 4; i++)
#pragma unroll
        for (int j = 0; j < 4; j++)
            acc[4 + i][j] = __builtin_amdgcn_mfma_f32_16x16x32_bf16(a2[i], b[j], acc[4 + i][j], 0, 0, 0);
    __builtin_amdgcn_s_setprio(0);

    // ---- P3: acc[0..3], kstep1 ----
#pragma unroll
    for (int j = 0; j < 4; j++)
        b[j] = *(const shortx8*)&Br[(wn + j * 16 + r16) * 64 + c1 * 8];
#pragma unroll
    for (int i = 0; i < 4; i++)
        a[i] = *(const shortx8*)&Ar[(wm + i * 16 + r16) * 64 + c1 * 8];
    if constexpr (MODE <= 1) {
        ld_lds16(gA1 +  64 * K, dA1 +  64 * 64);   // Aq1 of u+1
        ld_lds16(gA1 + 192 * K, dA1 + 192 * 64);   // Aq3
    }
    __builtin_amdgcn_s_setprio(1);
#pragma unroll
    for (int i = 0; i < 4; i++)
#pragma unroll
        for (int j = 0; j < 4; j++)
            acc[i][j] = __builtin_amdgcn_mfma_f32_16x16x32_bf16(a[i], b[j], acc[i][j], 0, 0, 0);
    __builtin_amdgcn_s_setprio(0);
    if constexpr (MODE == 0)
        asm volatile("s_barrier" ::: "memory");            // P4pre (B WAR)

    // ---- P4: acc[4..7], kstep1 ----
#pragma unroll
    for (int i = 0; i < 4; i++)
        a2[i] = *(const shortx8*)&Ar[(wm + 64 + i * 16 + r16) * 64 + c1 * 8];
    if constexpr (MODE == 0) {
        ld_lds16(gB1 + 64,          dBc);              // Bq0 of u+2 -> current buf
        ld_lds16(gB1 + 64 + 64 * K, dBc + 64 * 64);    // Bq1
    }
    __builtin_amdgcn_s_setprio(1);
#pragma unroll
    for (int i = 0; i < 4; i++)
#pragma unroll
        for (int j = 0; j < 4; j++)
            acc[4 + i][j] = __builtin_amdgcn_mfma_f32_16x16x32_bf16(a2[i], b[j], acc[4 + i][j], 0, 0, 0);
    __builtin_amdgcn_s_setprio(0);
    if constexpr (MODE == 0) {
        asm volatile("s_waitcnt vmcnt(2)" ::: "memory");   // drain W[u]: tile u+1 done
        asm volatile("s_barrier" ::: "memory");            // P4post: publish, buf switch
    } else if constexpr (MODE == 1) {
        asm volatile("s_waitcnt vmcnt(0)" ::: "memory");   // tail: tile 63 lands
        asm volatile("s_barrier" ::: "memory");
    }                                                      // MODE 2: no sync at all
}

__global__ __launch_bounds__(512, 2) void gemm_bt(const u16* __restrict__ A,
                                                  const u16* __restrict__ B,
                                                  float* __restrict__ C) {
    constexpr size_t K = 4096;
    constexpr int N = 4096;
    __shared__ __align__(16) u16 As[2][BM * BK];   // 2 x 32 KiB
    __shared__ __align__(16) u16 Bs[2][BN * BK];   // 2 x 32 KiB -> 128 KiB

    const int t    = threadIdx.x;
    const int wave = t >> 6;
    const int lane = t & 63;
    const int quad = lane >> 4;
    const int r16  = lane & 15;

    // XCD swizzle (512 blocks, 512%8==0 bijective): 4 m-tiles x 16 n-tiles per XCD
    const int id  = blockIdx.x;
    const int xcd = id & 7;
    const int loc = id >> 3;                       // 0..63
    const int bm  = (xcd * 4 + (loc >> 4)) * BM;   // 0..31 * 256
    const int bn  = (loc & 15) * BN;               // 0..15 * 256

    // per-lane staging source (pre-swizzled chunk): row w*8+(lane>>3), chunk (lane&7)^(lane>>3)
    const int lrow = (wave << 3) + (lane >> 3);
    const int lch  = (lane & 7) ^ (lane >> 3);
    const u16* sA = A + (size_t)(bm + lrow) * K + lch * 8;
    const u16* sB = B + (size_t)(bn + lrow) * K + lch * 8;

    const int w512 = wave * 512;                   // wave slab offset within a quarter
    u16* dA0 = &As[0][w512];  u16* dA1 = &As[1][w512];
    u16* dB0 = &Bs[0][w512];  u16* dB1 = &Bs[1][w512];

    const int wm = (wave >> 2) * 128;              // wave tile 128(m) x 64(n)
    const int wn = (wave & 3) * 64;
    const int c0 = quad ^ (r16 & 7);               // kstep0 chunk key
    const int c1 = c0 ^ 4;                         // kstep1

    f32x4 acc[8][4];
#pragma unroll
    for (int i = 0; i < 8; i++)
#pragma unroll
        for (int j = 0; j < 4; j++) acc[i][j] = (f32x4)0.0f;

    // prologue: tile 0 (8 quarters) -> buf0; tile 1 Bq0,Bq1 -> buf1.
#pragma unroll
    for (int r0 = 0; r0 < 256; r0 += 64) {
        ld_lds16(sA + (size_t)r0 * K, dA0 + r0 * 64);
        ld_lds16(sB + (size_t)r0 * K, dB0 + r0 * 64);
    }
    ld_lds16(sB + 64,                  dB1);
    ld_lds16(sB + 64 + (size_t)64 * K, dB1 + 64 * 64);
    asm volatile("s_waitcnt vmcnt(2)" ::: "memory");   // tile 0 landed; Bq01(1) in flight
    asm volatile("s_barrier" ::: "memory");

    const u16* gA1 = sA + 64;   // staging src base, tile u+1
    const u16* gB1 = sB + 64;
#pragma unroll 1
    for (int u = 0; u < 62; u += 2) {
        kgroup<0>(As[0], Bs[0], dA1, dB1, dB0, gA1, gB1, wm, wn, r16, c0, c1, acc);
        gA1 += 64; gB1 += 64;
        kgroup<0>(As[1], Bs[1], dA0, dB0, dB1, gA1, gB1, wm, wn, r16, c0, c1, acc);
        gA1 += 64; gB1 += 64;
    }
    // group 62 (buf0; stages tile 63 into buf1 at P1-P3; vmcnt(0)), group 63 (buf1)
    kgroup<1>(As[0], Bs[0], dA1, dB1, dB0, gA1, gB1, wm, wn, r16, c0, c1, acc);
    kgroup<2>(As[1], Bs[1], dA0, dB0, dB1, gA1, gB1, wm, wn, r16, c0, c1, acc);

    // epilogue: C/D layout col=lane&15, row=quad*4+reg  [verified m89; refcheck'd]
#pragma unroll
    for (int i = 0; i < 8; i++) {
        const int row0 = bm + wm + i * 16 + quad * 4;
#pragma unroll
        for (int j = 0; j < 4; j++) {
            const int col = bn + wn + j * 16 + r16;
            float* cp = &C[(size_t)row0 * N + col];
#pragma unroll
            for (int v = 0; v < 4; ++v)
                cp[(size_t)v * N] = acc[i][j][v];
        }
    }
}

// ---------------- fallback (ws too small): fp32 tiled, dequant on the fly ----------------

__global__ __launch_bounds__(256) void fallback_gemm(const float* __restrict__ x,
                                                     const int* __restrict__ qi,
                                                     const float* __restrict__ sc,
                                                     float* __restrict__ y) {
    __shared__ float xs[16][16];
    __shared__ float wsm[16][17];
    const int tx = threadIdx.x, ty = threadIdx.y;
    const int m = blockIdx.y * 16 + ty;
    const int nrow = blockIdx.x * 16 + ty;   // W row loaded by this thread
    float acc = 0.f;
    for (int k0 = 0; k0 < 4096; k0 += 16) {
        xs[ty][tx] = x[(size_t)m * 4096 + k0 + tx];
        const size_t fi = (size_t)nrow * 4096 + k0 + tx;
        wsm[ty][tx] = NF4C[qi[fi]] * sc[fi >> 10];
        __syncthreads();
#pragma unroll
        for (int kk = 0; kk < 16; kk++) acc += xs[ty][kk] * wsm[tx][kk];
        __syncthreads();
    }
    y[(size_t)m * 4096 + blockIdx.x * 16 + tx] = acc;
}

// ---------------- launch ----------------

extern "C" void kernel_launch(void* const* d_in, const int* in_sizes, int n_in,
                              void* d_out, int out_size, void* d_ws, size_t ws_size,
                              hipStream_t stream) {
    const float* x  = (const float*)d_in[0];
    const int*   qi = (const int*)d_in[1];
    const float* sc = (const float*)d_in[2];
    float* y = (float*)d_out;

    const int M = 8192, N = 4096, K = 4096;
    const size_t xb_bytes = (size_t)M * K * 2;   // 64 MiB
    const size_t wb_bytes = (size_t)N * K * 2;   // 32 MiB

    if (ws_size >= xb_bytes + wb_bytes) {
        u16* xb = (u16*)d_ws;
        u16* wb = (u16*)((char*)d_ws + xb_bytes);
        prep<<<2048, 256, 0, stream>>>(x, qi, sc, xb, wb);
        gemm_bt<<<(M / BM) * (N / BN), 512, 0, stream>>>(xb, wb, y);
    } else {
        dim3 block(16, 16);
        dim3 grid(N / 16, M / 16);
        fallback_gemm<<<grid, block, 0, stream>>>(x, qi, sc, y);
    }
}